// Round 9
// baseline (637.595 us; speedup 1.0000x reference)
//
#include <hip/hip_runtime.h>
#include <hip/hip_fp16.h>

#define NN 50000
#define EE 800000

typedef float f32x4 __attribute__((ext_vector_type(4)));
typedef _Float16 f16x8 __attribute__((ext_vector_type(8)));
typedef _Float16 f16x4 __attribute__((ext_vector_type(4)));
typedef _Float16 f16x2 __attribute__((ext_vector_type(2)));

// ---------------------------------------------------------------------------
// CSR build
// ---------------------------------------------------------------------------
__global__ void hist_kernel(const int* __restrict__ dst, int* __restrict__ counts, int E) {
    int idx = blockIdx.x * blockDim.x + threadIdx.x;
    int stride = gridDim.x * blockDim.x;
    for (int e = idx; e < E; e += stride)
        atomicAdd(&counts[dst[e]], 1);
}

__global__ void scan_kernel(const int* __restrict__ counts, int* __restrict__ row_off, int n) {
    __shared__ int sums[1024];
    int t = threadIdx.x;
    int chunk = (n + 1023) >> 10;
    int lo = t * chunk;
    int hi = min(lo + chunk, n);
    int s = 0;
    for (int i = lo; i < hi; ++i) s += counts[i];
    sums[t] = s;
    __syncthreads();
    for (int off = 1; off < 1024; off <<= 1) {
        int v = (t >= off) ? sums[t - off] : 0;
        __syncthreads();
        sums[t] += v;
        __syncthreads();
    }
    int run = (t == 0) ? 0 : sums[t - 1];
    for (int i = lo; i < hi; ++i) { row_off[i] = run; run += counts[i]; }
    if (t == 1023) row_off[n] = sums[1023];
}

__global__ void scatter_kernel(const int* __restrict__ src, const int* __restrict__ dst,
                               const int* __restrict__ row_off, int* __restrict__ cursor,
                               int* __restrict__ esrc, int E) {
    int idx = blockIdx.x * blockDim.x + threadIdx.x;
    int stride = gridDim.x * blockDim.x;
    for (int e = idx; e < E; e += stride) {
        int d = dst[e];
        int pos = row_off[d] + atomicAdd(&cursor[d], 1);
        esrc[pos] = src[e];
    }
}

// ---------------------------------------------------------------------------
// Fused prep: weights -> transposed fp16 [Nc][K] (Wl/Wr concat), x -> fp16.
// ---------------------------------------------------------------------------
__global__ void prep_all(const float* __restrict__ Wl1, const float* __restrict__ Wr1,
                         const float* __restrict__ Wl2, const float* __restrict__ Wr2,
                         const float* __restrict__ Wl3, const float* __restrict__ Wr3,
                         const float* __restrict__ Wlin,
                         __half* __restrict__ w1, __half* __restrict__ w2,
                         __half* __restrict__ w3, __half* __restrict__ w4,
                         const float* __restrict__ x, __half* __restrict__ xf, int n4x) {
    int idx = blockIdx.x * blockDim.x + threadIdx.x;
    if (idx < 233472) {
        const float* W; __half* o; int K, Nc, roff, li;
        if (idx < 65536) {
            K = 128; Nc = 256; o = w1;
            if (idx < 32768) { W = Wl1; li = idx; roff = 0; }
            else             { W = Wr1; li = idx - 32768; roff = 256; }
        } else if (idx < 196608) {
            K = 256; Nc = 256; o = w2;
            if (idx < 131072) { W = Wl2; li = idx - 65536; roff = 0; }
            else              { W = Wr2; li = idx - 131072; roff = 256; }
        } else if (idx < 229376) {
            K = 256; Nc = 64; o = w3;
            if (idx < 212992) { W = Wl3; li = idx - 196608; roff = 0; }
            else              { W = Wr3; li = idx - 212992; roff = 64; }
        } else {
            K = 64; Nc = 64; o = w4; W = Wlin; li = idx - 229376; roff = 0;
        }
        int k = li / Nc, n = li - k * Nc;
        o[(size_t)(roff + n) * K + k] = __float2half_rn(W[li]);
    } else {
        int xi = idx - 233472;
        if (xi < n4x) {
            float4 v = *(const float4*)(x + (size_t)xi * 4);
            f16x4 h = {(_Float16)v.x, (_Float16)v.y, (_Float16)v.z, (_Float16)v.w};
            *(f16x4*)((_Float16*)xf + (size_t)xi * 4) = h;
        }
    }
}

// ---------------------------------------------------------------------------
// Weight-stationary tall-skinny GEMM (structure from R7): no LDS, no
// barriers, B resident in VGPRs for all K, A global->reg in MFMA layout,
// grid-stride tiles with A double-buffer. Grid sized so every CU has
// multiple blocks queued (R9: was 1 block/CU resident -> latency-exposed).
// ---------------------------------------------------------------------------
template <int KS, int COLG>
__global__ __launch_bounds__(COLG * 256) void gemm_ws(
        const __half* __restrict__ A, const __half* __restrict__ Bt,
        int M, int nTiles, int Nc, int splitCol,
        __half* __restrict__ outL, __half* __restrict__ outR,
        float* __restrict__ outF, const float* __restrict__ bias) {
    constexpr int K = KS * 32;
    int tid = threadIdx.x;
    int lane = tid & 63;
    int w = tid >> 6;
    int rs = w & 3;
    int cg = w >> 2;
    int l15 = lane & 15, q = lane >> 4;
    int colbase = blockIdx.y * (COLG * 64) + cg * 64;

    const _Float16* Ap = (const _Float16*)A;
    const _Float16* Bp = (const _Float16*)Bt;

    f16x8 bfrag[KS][4];
#pragma unroll
    for (int ks = 0; ks < KS; ++ks)
#pragma unroll
        for (int ni = 0; ni < 4; ++ni)
            bfrag[ks][ni] = *(const f16x8*)(Bp + (size_t)(colbase + ni * 16 + l15) * K + ks * 32 + q * 8);

    int tile = blockIdx.x;
    if (tile >= nTiles) return;

    f16x8 afrag[KS];
    {
        int row = tile * 64 + rs * 16 + l15;
        if (row >= M) row = M - 1;
        const _Float16* ap = Ap + (size_t)row * K + q * 8;
#pragma unroll
        for (int ks = 0; ks < KS; ++ks) afrag[ks] = *(const f16x8*)(ap + ks * 32);
    }

    while (true) {
        int next = tile + gridDim.x;
        bool has = (next < nTiles);
        f16x8 anext[KS];
        if (has) {
            int row = next * 64 + rs * 16 + l15;
            if (row >= M) row = M - 1;
            const _Float16* ap = Ap + (size_t)row * K + q * 8;
#pragma unroll
            for (int ks = 0; ks < KS; ++ks) anext[ks] = *(const f16x8*)(ap + ks * 32);
        }

        f32x4 acc[4] = {};
#pragma unroll
        for (int ks = 0; ks < KS; ++ks)
#pragma unroll
            for (int ni = 0; ni < 4; ++ni)
                acc[ni] = __builtin_amdgcn_mfma_f32_16x16x32_f16(afrag[ks], bfrag[ks][ni], acc[ni], 0, 0, 0);

#pragma unroll
        for (int ni = 0; ni < 4; ++ni) {
            int gc = colbase + ni * 16 + l15;
            if (outF) {
                float bv = bias ? bias[gc] : 0.f;
#pragma unroll
                for (int r = 0; r < 4; ++r) {
                    int gr = tile * 64 + rs * 16 + q * 4 + r;
                    if (gr < M) outF[(size_t)gr * Nc + gc] = acc[ni][r] + bv;
                }
            } else {
                __half* dp = outL; int cc = gc;
                if (gc >= splitCol) { dp = outR; cc = gc - splitCol; }
#pragma unroll
                for (int r = 0; r < 4; ++r) {
                    int gr = tile * 64 + rs * 16 + q * 4 + r;
                    if (gr < M) dp[(size_t)gr * splitCol + cc] = __float2half_rn(acc[ni][r]);
                }
            }
        }
        if (!has) break;
#pragma unroll
        for (int ks = 0; ks < KS; ++ks) afrag[ks] = anext[ks];
        tile = next;
    }
}

// ---------------------------------------------------------------------------
// GATv2 gather, H=4 x C=64, fp16 in/out. One wave per dst node, 2 edges per
// wave-pass (half-waves), unroll x2. R9 diet: 32-bit vector offsets (1 addr
// op/edge), accumulation via fmaf(p,(float)v,acc) -> v_fma_mix_f32 (no
// separate cvts). att pre-scaled by log2(e) -> exp2f.
// ---------------------------------------------------------------------------
__global__ __launch_bounds__(256) void gat_gather_h4(
        const __half* __restrict__ xl, const __half* __restrict__ xr,
        const float* __restrict__ att, const float* __restrict__ bias,
        const int* __restrict__ row_off, const int* __restrict__ esrc,
        __half* __restrict__ out, int n) {
    const float LOG2E = 1.44269504f;
    int wave = threadIdx.x >> 6;
    int lane = threadIdx.x & 63;
    int node = blockIdx.x * 4 + wave;
    if (node >= n) return;
    int half = lane >> 5;
    unsigned j = lane & 31;

    const uint4* xl4 = (const uint4*)xl;
    uint4 xraw = ((const uint4*)xr)[((unsigned)node << 5) + j];
    f16x2 xrv[4] = {*(const f16x2*)&xraw.x, *(const f16x2*)&xraw.y,
                    *(const f16x2*)&xraw.z, *(const f16x2*)&xraw.w};
    float4 aA = *(const float4*)(att + j * 8);
    float4 aB = *(const float4*)(att + j * 8 + 4);
    f16x2 atv[4] = {{(_Float16)(aA.x * LOG2E), (_Float16)(aA.y * LOG2E)},
                    {(_Float16)(aA.z * LOG2E), (_Float16)(aA.w * LOG2E)},
                    {(_Float16)(aB.x * LOG2E), (_Float16)(aB.y * LOG2E)},
                    {(_Float16)(aB.z * LOG2E), (_Float16)(aB.w * LOG2E)}};
    const f16x2 k02 = {(_Float16)0.2f, (_Float16)0.2f};

    float acc0[8] = {}, acc1[8] = {};
    float l0 = 0.f, l1 = 0.f;

    int e0 = row_off[node], e1 = row_off[node + 1];
    int elast = e1 - 1;

#define H4_BODY(EBASE, ACC, LSUM)                                             \
    {                                                                         \
        int idx_ = EBASE + half;                                              \
        int s_ = esrc[min(idx_, elast)];                                      \
        uint4 raw_ = xl4[((unsigned)s_ << 5) + j];                            \
        f16x2 v0_ = *(const f16x2*)&raw_.x;                                   \
        f16x2 v1_ = *(const f16x2*)&raw_.y;                                   \
        f16x2 v2_ = *(const f16x2*)&raw_.z;                                   \
        f16x2 v3_ = *(const f16x2*)&raw_.w;                                   \
        f16x2 s0_ = v0_ + xrv[0], s1_ = v1_ + xrv[1];                         \
        f16x2 s2_ = v2_ + xrv[2], s3_ = v3_ + xrv[3];                         \
        f16x2 r0_ = __builtin_elementwise_max(s0_, s0_ * k02);                \
        f16x2 r1_ = __builtin_elementwise_max(s1_, s1_ * k02);                \
        f16x2 r2_ = __builtin_elementwise_max(s2_, s2_ * k02);                \
        f16x2 r3_ = __builtin_elementwise_max(s3_, s3_ * k02);                \
        float t_ = __builtin_amdgcn_fdot2(r0_, atv[0], 0.f, false);           \
        t_ = __builtin_amdgcn_fdot2(r1_, atv[1], t_, false);                  \
        t_ = __builtin_amdgcn_fdot2(r2_, atv[2], t_, false);                  \
        t_ = __builtin_amdgcn_fdot2(r3_, atv[3], t_, false);                  \
        t_ += __shfl_xor(t_, 1);                                              \
        t_ += __shfl_xor(t_, 2);                                              \
        t_ += __shfl_xor(t_, 4);                                              \
        float p_ = exp2f(t_);                                                 \
        p_ = (idx_ < e1) ? p_ : 0.f;                                          \
        LSUM += p_;                                                           \
        ACC[0] = fmaf((float)v0_.x, p_, ACC[0]);                              \
        ACC[1] = fmaf((float)v0_.y, p_, ACC[1]);                              \
        ACC[2] = fmaf((float)v1_.x, p_, ACC[2]);                              \
        ACC[3] = fmaf((float)v1_.y, p_, ACC[3]);                              \
        ACC[4] = fmaf((float)v2_.x, p_, ACC[4]);                              \
        ACC[5] = fmaf((float)v2_.y, p_, ACC[5]);                              \
        ACC[6] = fmaf((float)v3_.x, p_, ACC[6]);                              \
        ACC[7] = fmaf((float)v3_.y, p_, ACC[7]);                              \
    }

    for (int e = e0; e < e1; e += 4) {
        H4_BODY(e, acc0, l0)
        if (e + 2 < e1) H4_BODY(e + 2, acc1, l1)
    }
#undef H4_BODY

    float acc[8];
#pragma unroll
    for (int k = 0; k < 8; ++k) acc[k] = acc0[k] + acc1[k];
    float L = l0 + l1;
#pragma unroll
    for (int k = 0; k < 8; ++k) acc[k] += __shfl_xor(acc[k], 32);
    L += __shfl_xor(L, 32);

    float inv = 1.f / (L + 1e-16f);
    float4 bvA = *(const float4*)(bias + j * 8);
    float4 bvB = *(const float4*)(bias + j * 8 + 4);
    float bb[8] = {bvA.x, bvA.y, bvA.z, bvA.w, bvB.x, bvB.y, bvB.z, bvB.w};
    f16x8 ov;
#pragma unroll
    for (int k = 0; k < 8; ++k) {
        float v = acc[k] * inv + bb[k];
        v = v > 0.f ? v : __expf(v) - 1.f;   // ELU
        ov[k] = (_Float16)v;
    }
    if (half == 0)
        ((f16x8*)((_Float16*)out + ((size_t)node << 8)))[j] = ov;
}

// ---------------------------------------------------------------------------
// GATv2 gather, H=1 x C=64, fp16 in/out (no ELU). One wave per node,
// 4 edges per pass (16-lane quarters), unroll x2; same R9 diet.
// ---------------------------------------------------------------------------
__global__ __launch_bounds__(256) void gat_gather_h1(
        const __half* __restrict__ xl, const __half* __restrict__ xr,
        const float* __restrict__ att, const float* __restrict__ bias,
        const int* __restrict__ row_off, const int* __restrict__ esrc,
        __half* __restrict__ out, int n) {
    const float LOG2E = 1.44269504f;
    int wave = threadIdx.x >> 6;
    int lane = threadIdx.x & 63;
    int node = blockIdx.x * 4 + wave;
    if (node >= n) return;
    int q4 = lane >> 4;
    unsigned j = lane & 15;

    const uint2* xl2 = (const uint2*)xl;
    uint2 xraw = ((const uint2*)xr)[((unsigned)node << 4) + j];
    f16x2 xrv[2] = {*(const f16x2*)&xraw.x, *(const f16x2*)&xraw.y};
    float4 av = *(const float4*)(att + j * 4);
    f16x2 atv[2] = {{(_Float16)(av.x * LOG2E), (_Float16)(av.y * LOG2E)},
                    {(_Float16)(av.z * LOG2E), (_Float16)(av.w * LOG2E)}};
    const f16x2 k02 = {(_Float16)0.2f, (_Float16)0.2f};

    float acc0[4] = {}, acc1[4] = {};
    float l0 = 0.f, l1 = 0.f;

    int e0 = row_off[node], e1 = row_off[node + 1];
    int elast = e1 - 1;

#define H1_BODY(EBASE, ACC, LSUM)                                             \
    {                                                                         \
        int idx_ = EBASE + q4;                                                \
        int s_ = esrc[min(idx_, elast)];                                      \
        uint2 raw_ = xl2[((unsigned)s_ << 4) + j];                            \
        f16x2 v0_ = *(const f16x2*)&raw_.x;                                   \
        f16x2 v1_ = *(const f16x2*)&raw_.y;                                   \
        f16x2 s0_ = v0_ + xrv[0], s1_ = v1_ + xrv[1];                         \
        f16x2 r0_ = __builtin_elementwise_max(s0_, s0_ * k02);                \
        f16x2 r1_ = __builtin_elementwise_max(s1_, s1_ * k02);                \
        float t_ = __builtin_amdgcn_fdot2(r0_, atv[0], 0.f, false);           \
        t_ = __builtin_amdgcn_fdot2(r1_, atv[1], t_, false);                  \
        t_ += __shfl_xor(t_, 1);                                              \
        t_ += __shfl_xor(t_, 2);                                              \
        t_ += __shfl_xor(t_, 4);                                              \
        t_ += __shfl_xor(t_, 8);                                              \
        float p_ = exp2f(t_);                                                 \
        p_ = (idx_ < e1) ? p_ : 0.f;                                          \
        LSUM += p_;                                                           \
        ACC[0] = fmaf((float)v0_.x, p_, ACC[0]);                              \
        ACC[1] = fmaf((float)v0_.y, p_, ACC[1]);                              \
        ACC[2] = fmaf((float)v1_.x, p_, ACC[2]);                              \
        ACC[3] = fmaf((float)v1_.y, p_, ACC[3]);                              \
    }

    for (int e = e0; e < e1; e += 8) {
        H1_BODY(e, acc0, l0)
        if (e + 4 < e1) H1_BODY(e + 4, acc1, l1)
    }
#undef H1_BODY

    float acc[4];
#pragma unroll
    for (int k = 0; k < 4; ++k) acc[k] = acc0[k] + acc1[k];
    float L = l0 + l1;
#pragma unroll
    for (int k = 0; k < 4; ++k) {
        acc[k] += __shfl_xor(acc[k], 16);
        acc[k] += __shfl_xor(acc[k], 32);
    }
    L += __shfl_xor(L, 16);
    L += __shfl_xor(L, 32);

    float inv = 1.f / (L + 1e-16f);
    float4 bv = *(const float4*)(bias + j * 4);
    f16x4 ov = {(_Float16)(acc[0] * inv + bv.x),
                (_Float16)(acc[1] * inv + bv.y),
                (_Float16)(acc[2] * inv + bv.z),
                (_Float16)(acc[3] * inv + bv.w)};
    if (q4 == 0)
        ((f16x4*)((_Float16*)out + ((size_t)node << 6)))[j] = ov;
}

// ---------------------------------------------------------------------------
extern "C" void kernel_launch(void* const* d_in, const int* in_sizes, int n_in,
                              void* d_out, int out_size, void* d_ws, size_t ws_size,
                              hipStream_t stream) {
    const float* x    = (const float*)d_in[0];
    const float* Wl1  = (const float*)d_in[1];
    const float* Wr1  = (const float*)d_in[2];
    const float* att1 = (const float*)d_in[3];
    const float* b1   = (const float*)d_in[4];
    const float* Wl2  = (const float*)d_in[5];
    const float* Wr2  = (const float*)d_in[6];
    const float* att2 = (const float*)d_in[7];
    const float* b2   = (const float*)d_in[8];
    const float* Wl3  = (const float*)d_in[9];
    const float* Wr3  = (const float*)d_in[10];
    const float* att3 = (const float*)d_in[11];
    const float* b3   = (const float*)d_in[12];
    const float* Wlin = (const float*)d_in[13];
    const float* blin = (const float*)d_in[14];
    const int*   ei   = (const int*)d_in[15];
    const int* src = ei;
    const int* dst = ei + EE;

    const int N = NN, E = EE;

    __half* xf = (__half*)d_ws;                 // N*128
    __half* xl = xf + (size_t)N * 128;          // N*256
    __half* xr = xl + (size_t)N * 256;          // N*256
    __half* H  = xr + (size_t)N * 256;          // N*256
    __half* G  = H + (size_t)N * 256;           // N*64
    __half* w1 = G + (size_t)N * 64;            // 65536  [512][128]
    __half* w2 = w1 + 65536;                    // 131072 [512][256]
    __half* w3 = w2 + 131072;                   // 32768  [128][256]
    __half* w4 = w3 + 32768;                    // 4096   [64][64]
    int* row_off = (int*)(w4 + 4096);           // N+1
    int* tmp     = row_off + (N + 1);           // 2N (counts | cursor)
    int* esrc    = tmp + 2 * N;                 // E

    // --- build CSR by dst ---
    hipMemsetAsync(tmp, 0, (size_t)2 * N * sizeof(int), stream);
    hist_kernel<<<1024, 256, 0, stream>>>(dst, tmp, E);
    scan_kernel<<<1, 1024, 0, stream>>>(tmp, row_off, N);
    scatter_kernel<<<1024, 256, 0, stream>>>(src, dst, row_off, tmp + N, esrc, E);

    // --- weights + x -> fp16 (one launch) ---
    int n4x = N * 128 / 4;
    prep_all<<<(233472 + n4x + 255) / 256, 256, 0, stream>>>(
        Wl1, Wr1, Wl2, Wr2, Wl3, Wr3, Wlin, w1, w2, w3, w4, x, xf, n4x);

    int nTiles = (N + 63) / 64;                 // 782
    int gatherBlocks = (N + 3) / 4;

    // --- layer 1: xf[128] @ w1 -> xl,xr fp16 ---
    gemm_ws<4, 2><<<dim3(391, 4), 512, 0, stream>>>(
        xf, w1, N, nTiles, 512, 256, xl, xr, nullptr, nullptr);
    gat_gather_h4<<<gatherBlocks, 256, 0, stream>>>(xl, xr, att1, b1, row_off, esrc, H, N);

    // --- layer 2: H[256] @ w2 -> xl,xr ---
    gemm_ws<8, 2><<<dim3(391, 4), 512, 0, stream>>>(
        H, w2, N, nTiles, 512, 256, xl, xr, nullptr, nullptr);
    gat_gather_h4<<<gatherBlocks, 256, 0, stream>>>(xl, xr, att2, b2, row_off, esrc, H, N);

    // --- layer 3: H[256] @ w3 -> xl,xr ([N][64] each) ---
    gemm_ws<8, 2><<<dim3(391, 1), 512, 0, stream>>>(
        H, w3, N, nTiles, 128, 64, xl, xr, nullptr, nullptr);
    gat_gather_h1<<<gatherBlocks, 256, 0, stream>>>(xl, xr, att3, b3, row_off, esrc, G, N);

    // --- final: G[64] @ w4 + blin -> d_out fp32 ---
    gemm_ws<2, 1><<<dim3(782, 1), 256, 0, stream>>>(
        G, w4, N, nTiles, 64, 64, nullptr, nullptr, (float*)d_out, blin);
}

// Round 10
// 555.180 us; speedup vs baseline: 1.1484x; 1.1484x over previous
//
#include <hip/hip_runtime.h>
#include <hip/hip_fp16.h>

#define NN 50000
#define EE 800000

typedef float f32x4 __attribute__((ext_vector_type(4)));
typedef _Float16 f16x8 __attribute__((ext_vector_type(8)));
typedef _Float16 f16x4 __attribute__((ext_vector_type(4)));
typedef _Float16 f16x2 __attribute__((ext_vector_type(2)));

// ---------------------------------------------------------------------------
// CSR build
// ---------------------------------------------------------------------------
__global__ void hist_kernel(const int* __restrict__ dst, int* __restrict__ counts, int E) {
    int idx = blockIdx.x * blockDim.x + threadIdx.x;
    int stride = gridDim.x * blockDim.x;
    for (int e = idx; e < E; e += stride)
        atomicAdd(&counts[dst[e]], 1);
}

__global__ void scan_kernel(const int* __restrict__ counts, int* __restrict__ row_off, int n) {
    __shared__ int sums[1024];
    int t = threadIdx.x;
    int chunk = (n + 1023) >> 10;
    int lo = t * chunk;
    int hi = min(lo + chunk, n);
    int s = 0;
    for (int i = lo; i < hi; ++i) s += counts[i];
    sums[t] = s;
    __syncthreads();
    for (int off = 1; off < 1024; off <<= 1) {
        int v = (t >= off) ? sums[t - off] : 0;
        __syncthreads();
        sums[t] += v;
        __syncthreads();
    }
    int run = (t == 0) ? 0 : sums[t - 1];
    for (int i = lo; i < hi; ++i) { row_off[i] = run; run += counts[i]; }
    if (t == 1023) row_off[n] = sums[1023];
}

__global__ void scatter_kernel(const int* __restrict__ src, const int* __restrict__ dst,
                               const int* __restrict__ row_off, int* __restrict__ cursor,
                               int* __restrict__ esrc, int E) {
    int idx = blockIdx.x * blockDim.x + threadIdx.x;
    int stride = gridDim.x * blockDim.x;
    for (int e = idx; e < E; e += stride) {
        int d = dst[e];
        int pos = row_off[d] + atomicAdd(&cursor[d], 1);
        esrc[pos] = src[e];
    }
}

// ---------------------------------------------------------------------------
// Fused prep: weights -> FRAGMENT-READY fp16 layout (R10), x -> fp16.
// Fragment layout for weight [Nc_tot cols][K]:
//   col -> cgni = col>>4, l15 = col&15 ; k -> ks = k>>5, q=(k>>3)&3, e=k&7
//   flat = ((cgni*KS + ks)*64 + q*16 + l15)*8 + e
// so a wave's bfrag[ks][ni] load is 64 lanes x consecutive 16B = 1KB burst.
// ---------------------------------------------------------------------------
__device__ __forceinline__ void wfrag_store(__half* o, int K, int col, int k, float v) {
    int KS = K >> 5;
    int cgni = col >> 4, l15 = col & 15;
    int ks = k >> 5, qq = (k >> 3) & 3, ee = k & 7;
    size_t flat = ((size_t)(cgni * KS + ks) * 64 + qq * 16 + l15) * 8 + ee;
    o[flat] = __float2half_rn(v);
}

__global__ void prep_all(const float* __restrict__ Wl1, const float* __restrict__ Wr1,
                         const float* __restrict__ Wl2, const float* __restrict__ Wr2,
                         const float* __restrict__ Wl3, const float* __restrict__ Wr3,
                         const float* __restrict__ Wlin,
                         __half* __restrict__ w1, __half* __restrict__ w2,
                         __half* __restrict__ w3, __half* __restrict__ w4,
                         const float* __restrict__ x, __half* __restrict__ xf, int n4x) {
    int idx = blockIdx.x * blockDim.x + threadIdx.x;
    if (idx < 233472) {
        const float* W; __half* o; int K, Nc, roff, li;
        if (idx < 65536) {
            K = 128; Nc = 256; o = w1;
            if (idx < 32768) { W = Wl1; li = idx; roff = 0; }
            else             { W = Wr1; li = idx - 32768; roff = 256; }
        } else if (idx < 196608) {
            K = 256; Nc = 256; o = w2;
            if (idx < 131072) { W = Wl2; li = idx - 65536; roff = 0; }
            else              { W = Wr2; li = idx - 131072; roff = 256; }
        } else if (idx < 229376) {
            K = 256; Nc = 64; o = w3;
            if (idx < 212992) { W = Wl3; li = idx - 196608; roff = 0; }
            else              { W = Wr3; li = idx - 212992; roff = 64; }
        } else {
            K = 64; Nc = 64; o = w4; W = Wlin; li = idx - 229376; roff = 0;
        }
        int k = li / Nc, n = li - k * Nc;
        wfrag_store(o, K, roff + n, k, W[li]);
    } else {
        int xi = idx - 233472;
        if (xi < n4x) {
            float4 v = *(const float4*)(x + (size_t)xi * 4);
            f16x4 h = {(_Float16)v.x, (_Float16)v.y, (_Float16)v.z, (_Float16)v.w};
            *(f16x4*)((_Float16*)xf + (size_t)xi * 4) = h;
        }
    }
}

// ---------------------------------------------------------------------------
// Weight-stationary tall-skinny GEMM: no LDS, no barriers. B pre-permuted
// to fragment-ready layout -> coalesced 1KB bursts (R10 fix; R9's
// uncoalesced per-col loads caused a latency collapse at low tiles/block).
// A global->reg in MFMA layout (16 full 64B lines per b128). Grid-stride
// tiles with A double-buffer.
// ---------------------------------------------------------------------------
template <int KS, int COLG>
__global__ __launch_bounds__(COLG * 256) void gemm_ws(
        const __half* __restrict__ A, const __half* __restrict__ Bt,
        int M, int nTiles, int Nc, int splitCol,
        __half* __restrict__ outL, __half* __restrict__ outR,
        float* __restrict__ outF, const float* __restrict__ bias) {
    constexpr int K = KS * 32;
    int tid = threadIdx.x;
    int lane = tid & 63;
    int w = tid >> 6;
    int rs = w & 3;
    int cg = w >> 2;
    int l15 = lane & 15, q = lane >> 4;
    int colbase = blockIdx.y * (COLG * 64) + cg * 64;

    const _Float16* Ap = (const _Float16*)A;
    const f16x8* Bf = (const f16x8*)Bt;
    int cgni0 = (blockIdx.y * COLG + cg) * 4;

    f16x8 bfrag[KS][4];
#pragma unroll
    for (int ks = 0; ks < KS; ++ks)
#pragma unroll
        for (int ni = 0; ni < 4; ++ni)
            bfrag[ks][ni] = Bf[((size_t)(cgni0 + ni) * KS + ks) * 64 + lane];

    int tile = blockIdx.x;
    if (tile >= nTiles) return;

    f16x8 afrag[KS];
    {
        int row = tile * 64 + rs * 16 + l15;
        if (row >= M) row = M - 1;
        const _Float16* ap = Ap + (size_t)row * K + q * 8;
#pragma unroll
        for (int ks = 0; ks < KS; ++ks) afrag[ks] = *(const f16x8*)(ap + ks * 32);
    }

    while (true) {
        int next = tile + gridDim.x;
        bool has = (next < nTiles);
        f16x8 anext[KS];
        if (has) {
            int row = next * 64 + rs * 16 + l15;
            if (row >= M) row = M - 1;
            const _Float16* ap = Ap + (size_t)row * K + q * 8;
#pragma unroll
            for (int ks = 0; ks < KS; ++ks) anext[ks] = *(const f16x8*)(ap + ks * 32);
        }

        f32x4 acc[4] = {};
#pragma unroll
        for (int ks = 0; ks < KS; ++ks)
#pragma unroll
            for (int ni = 0; ni < 4; ++ni)
                acc[ni] = __builtin_amdgcn_mfma_f32_16x16x32_f16(afrag[ks], bfrag[ks][ni], acc[ni], 0, 0, 0);

#pragma unroll
        for (int ni = 0; ni < 4; ++ni) {
            int gc = colbase + ni * 16 + l15;
            if (outF) {
                float bv = bias ? bias[gc] : 0.f;
#pragma unroll
                for (int r = 0; r < 4; ++r) {
                    int gr = tile * 64 + rs * 16 + q * 4 + r;
                    if (gr < M) outF[(size_t)gr * Nc + gc] = acc[ni][r] + bv;
                }
            } else {
                __half* dp = outL; int cc = gc;
                if (gc >= splitCol) { dp = outR; cc = gc - splitCol; }
#pragma unroll
                for (int r = 0; r < 4; ++r) {
                    int gr = tile * 64 + rs * 16 + q * 4 + r;
                    if (gr < M) dp[(size_t)gr * splitCol + cc] = __float2half_rn(acc[ni][r]);
                }
            }
        }
        if (!has) break;
#pragma unroll
        for (int ks = 0; ks < KS; ++ks) afrag[ks] = anext[ks];
        tile = next;
    }
}

// ---------------------------------------------------------------------------
// GATv2 gather, H=4 x C=64, fp16 in/out. One wave per dst node, 2 edges per
// wave-pass (half-waves), unroll x2; 32-bit offsets, fma_mix accumulation,
// exp2f with pre-scaled att.
// ---------------------------------------------------------------------------
__global__ __launch_bounds__(256) void gat_gather_h4(
        const __half* __restrict__ xl, const __half* __restrict__ xr,
        const float* __restrict__ att, const float* __restrict__ bias,
        const int* __restrict__ row_off, const int* __restrict__ esrc,
        __half* __restrict__ out, int n) {
    const float LOG2E = 1.44269504f;
    int wave = threadIdx.x >> 6;
    int lane = threadIdx.x & 63;
    int node = blockIdx.x * 4 + wave;
    if (node >= n) return;
    int half = lane >> 5;
    unsigned j = lane & 31;

    const uint4* xl4 = (const uint4*)xl;
    uint4 xraw = ((const uint4*)xr)[((unsigned)node << 5) + j];
    f16x2 xrv[4] = {*(const f16x2*)&xraw.x, *(const f16x2*)&xraw.y,
                    *(const f16x2*)&xraw.z, *(const f16x2*)&xraw.w};
    float4 aA = *(const float4*)(att + j * 8);
    float4 aB = *(const float4*)(att + j * 8 + 4);
    f16x2 atv[4] = {{(_Float16)(aA.x * LOG2E), (_Float16)(aA.y * LOG2E)},
                    {(_Float16)(aA.z * LOG2E), (_Float16)(aA.w * LOG2E)},
                    {(_Float16)(aB.x * LOG2E), (_Float16)(aB.y * LOG2E)},
                    {(_Float16)(aB.z * LOG2E), (_Float16)(aB.w * LOG2E)}};
    const f16x2 k02 = {(_Float16)0.2f, (_Float16)0.2f};

    float acc0[8] = {}, acc1[8] = {};
    float l0 = 0.f, l1 = 0.f;

    int e0 = row_off[node], e1 = row_off[node + 1];
    int elast = e1 - 1;

#define H4_BODY(EBASE, ACC, LSUM)                                             \
    {                                                                         \
        int idx_ = EBASE + half;                                              \
        int s_ = esrc[min(idx_, elast)];                                      \
        uint4 raw_ = xl4[((unsigned)s_ << 5) + j];                            \
        f16x2 v0_ = *(const f16x2*)&raw_.x;                                   \
        f16x2 v1_ = *(const f16x2*)&raw_.y;                                   \
        f16x2 v2_ = *(const f16x2*)&raw_.z;                                   \
        f16x2 v3_ = *(const f16x2*)&raw_.w;                                   \
        f16x2 s0_ = v0_ + xrv[0], s1_ = v1_ + xrv[1];                         \
        f16x2 s2_ = v2_ + xrv[2], s3_ = v3_ + xrv[3];                         \
        f16x2 r0_ = __builtin_elementwise_max(s0_, s0_ * k02);                \
        f16x2 r1_ = __builtin_elementwise_max(s1_, s1_ * k02);                \
        f16x2 r2_ = __builtin_elementwise_max(s2_, s2_ * k02);                \
        f16x2 r3_ = __builtin_elementwise_max(s3_, s3_ * k02);                \
        float t_ = __builtin_amdgcn_fdot2(r0_, atv[0], 0.f, false);           \
        t_ = __builtin_amdgcn_fdot2(r1_, atv[1], t_, false);                  \
        t_ = __builtin_amdgcn_fdot2(r2_, atv[2], t_, false);                  \
        t_ = __builtin_amdgcn_fdot2(r3_, atv[3], t_, false);                  \
        t_ += __shfl_xor(t_, 1);                                              \
        t_ += __shfl_xor(t_, 2);                                              \
        t_ += __shfl_xor(t_, 4);                                              \
        float p_ = exp2f(t_);                                                 \
        p_ = (idx_ < e1) ? p_ : 0.f;                                          \
        LSUM += p_;                                                           \
        ACC[0] = fmaf((float)v0_.x, p_, ACC[0]);                              \
        ACC[1] = fmaf((float)v0_.y, p_, ACC[1]);                              \
        ACC[2] = fmaf((float)v1_.x, p_, ACC[2]);                              \
        ACC[3] = fmaf((float)v1_.y, p_, ACC[3]);                              \
        ACC[4] = fmaf((float)v2_.x, p_, ACC[4]);                              \
        ACC[5] = fmaf((float)v2_.y, p_, ACC[5]);                              \
        ACC[6] = fmaf((float)v3_.x, p_, ACC[6]);                              \
        ACC[7] = fmaf((float)v3_.y, p_, ACC[7]);                              \
    }

    for (int e = e0; e < e1; e += 4) {
        H4_BODY(e, acc0, l0)
        if (e + 2 < e1) H4_BODY(e + 2, acc1, l1)
    }
#undef H4_BODY

    float acc[8];
#pragma unroll
    for (int k = 0; k < 8; ++k) acc[k] = acc0[k] + acc1[k];
    float L = l0 + l1;
#pragma unroll
    for (int k = 0; k < 8; ++k) acc[k] += __shfl_xor(acc[k], 32);
    L += __shfl_xor(L, 32);

    float inv = 1.f / (L + 1e-16f);
    float4 bvA = *(const float4*)(bias + j * 8);
    float4 bvB = *(const float4*)(bias + j * 8 + 4);
    float bb[8] = {bvA.x, bvA.y, bvA.z, bvA.w, bvB.x, bvB.y, bvB.z, bvB.w};
    f16x8 ov;
#pragma unroll
    for (int k = 0; k < 8; ++k) {
        float v = acc[k] * inv + bb[k];
        v = v > 0.f ? v : __expf(v) - 1.f;   // ELU
        ov[k] = (_Float16)v;
    }
    if (half == 0)
        ((f16x8*)((_Float16*)out + ((size_t)node << 8)))[j] = ov;
}

// ---------------------------------------------------------------------------
// GATv2 gather, H=1 x C=64, fp16 in/out (no ELU). 4 edges per pass.
// ---------------------------------------------------------------------------
__global__ __launch_bounds__(256) void gat_gather_h1(
        const __half* __restrict__ xl, const __half* __restrict__ xr,
        const float* __restrict__ att, const float* __restrict__ bias,
        const int* __restrict__ row_off, const int* __restrict__ esrc,
        __half* __restrict__ out, int n) {
    const float LOG2E = 1.44269504f;
    int wave = threadIdx.x >> 6;
    int lane = threadIdx.x & 63;
    int node = blockIdx.x * 4 + wave;
    if (node >= n) return;
    int q4 = lane >> 4;
    unsigned j = lane & 15;

    const uint2* xl2 = (const uint2*)xl;
    uint2 xraw = ((const uint2*)xr)[((unsigned)node << 4) + j];
    f16x2 xrv[2] = {*(const f16x2*)&xraw.x, *(const f16x2*)&xraw.y};
    float4 av = *(const float4*)(att + j * 4);
    f16x2 atv[2] = {{(_Float16)(av.x * LOG2E), (_Float16)(av.y * LOG2E)},
                    {(_Float16)(av.z * LOG2E), (_Float16)(av.w * LOG2E)}};
    const f16x2 k02 = {(_Float16)0.2f, (_Float16)0.2f};

    float acc0[4] = {}, acc1[4] = {};
    float l0 = 0.f, l1 = 0.f;

    int e0 = row_off[node], e1 = row_off[node + 1];
    int elast = e1 - 1;

#define H1_BODY(EBASE, ACC, LSUM)                                             \
    {                                                                         \
        int idx_ = EBASE + q4;                                                \
        int s_ = esrc[min(idx_, elast)];                                      \
        uint2 raw_ = xl2[((unsigned)s_ << 4) + j];                            \
        f16x2 v0_ = *(const f16x2*)&raw_.x;                                   \
        f16x2 v1_ = *(const f16x2*)&raw_.y;                                   \
        f16x2 s0_ = v0_ + xrv[0], s1_ = v1_ + xrv[1];                         \
        f16x2 r0_ = __builtin_elementwise_max(s0_, s0_ * k02);                \
        f16x2 r1_ = __builtin_elementwise_max(s1_, s1_ * k02);                \
        float t_ = __builtin_amdgcn_fdot2(r0_, atv[0], 0.f, false);           \
        t_ = __builtin_amdgcn_fdot2(r1_, atv[1], t_, false);                  \
        t_ += __shfl_xor(t_, 1);                                              \
        t_ += __shfl_xor(t_, 2);                                              \
        t_ += __shfl_xor(t_, 4);                                              \
        t_ += __shfl_xor(t_, 8);                                              \
        float p_ = exp2f(t_);                                                 \
        p_ = (idx_ < e1) ? p_ : 0.f;                                          \
        LSUM += p_;                                                           \
        ACC[0] = fmaf((float)v0_.x, p_, ACC[0]);                              \
        ACC[1] = fmaf((float)v0_.y, p_, ACC[1]);                              \
        ACC[2] = fmaf((float)v1_.x, p_, ACC[2]);                              \
        ACC[3] = fmaf((float)v1_.y, p_, ACC[3]);                              \
    }

    for (int e = e0; e < e1; e += 8) {
        H1_BODY(e, acc0, l0)
        if (e + 4 < e1) H1_BODY(e + 4, acc1, l1)
    }
#undef H1_BODY

    float acc[4];
#pragma unroll
    for (int k = 0; k < 4; ++k) acc[k] = acc0[k] + acc1[k];
    float L = l0 + l1;
#pragma unroll
    for (int k = 0; k < 4; ++k) {
        acc[k] += __shfl_xor(acc[k], 16);
        acc[k] += __shfl_xor(acc[k], 32);
    }
    L += __shfl_xor(L, 16);
    L += __shfl_xor(L, 32);

    float inv = 1.f / (L + 1e-16f);
    float4 bv = *(const float4*)(bias + j * 4);
    f16x4 ov = {(_Float16)(acc[0] * inv + bv.x),
                (_Float16)(acc[1] * inv + bv.y),
                (_Float16)(acc[2] * inv + bv.z),
                (_Float16)(acc[3] * inv + bv.w)};
    if (q4 == 0)
        ((f16x4*)((_Float16*)out + ((size_t)node << 6)))[j] = ov;
}

// ---------------------------------------------------------------------------
extern "C" void kernel_launch(void* const* d_in, const int* in_sizes, int n_in,
                              void* d_out, int out_size, void* d_ws, size_t ws_size,
                              hipStream_t stream) {
    const float* x    = (const float*)d_in[0];
    const float* Wl1  = (const float*)d_in[1];
    const float* Wr1  = (const float*)d_in[2];
    const float* att1 = (const float*)d_in[3];
    const float* b1   = (const float*)d_in[4];
    const float* Wl2  = (const float*)d_in[5];
    const float* Wr2  = (const float*)d_in[6];
    const float* att2 = (const float*)d_in[7];
    const float* b2   = (const float*)d_in[8];
    const float* Wl3  = (const float*)d_in[9];
    const float* Wr3  = (const float*)d_in[10];
    const float* att3 = (const float*)d_in[11];
    const float* b3   = (const float*)d_in[12];
    const float* Wlin = (const float*)d_in[13];
    const float* blin = (const float*)d_in[14];
    const int*   ei   = (const int*)d_in[15];
    const int* src = ei;
    const int* dst = ei + EE;

    const int N = NN, E = EE;

    __half* xf = (__half*)d_ws;                 // N*128
    __half* xl = xf + (size_t)N * 128;          // N*256
    __half* xr = xl + (size_t)N * 256;          // N*256
    __half* H  = xr + (size_t)N * 256;          // N*256
    __half* G  = H + (size_t)N * 256;           // N*64
    __half* w1 = G + (size_t)N * 64;            // 65536  frag-layout
    __half* w2 = w1 + 65536;                    // 131072
    __half* w3 = w2 + 131072;                   // 32768
    __half* w4 = w3 + 32768;                    // 4096
    int* row_off = (int*)(w4 + 4096);           // N+1
    int* tmp     = row_off + (N + 1);           // 2N (counts | cursor)
    int* esrc    = tmp + 2 * N;                 // E

    // --- build CSR by dst ---
    hipMemsetAsync(tmp, 0, (size_t)2 * N * sizeof(int), stream);
    hist_kernel<<<1024, 256, 0, stream>>>(dst, tmp, E);
    scan_kernel<<<1, 1024, 0, stream>>>(tmp, row_off, N);
    scatter_kernel<<<1024, 256, 0, stream>>>(src, dst, row_off, tmp + N, esrc, E);

    // --- weights (fragment layout) + x -> fp16 ---
    int n4x = N * 128 / 4;
    prep_all<<<(233472 + n4x + 255) / 256, 256, 0, stream>>>(
        Wl1, Wr1, Wl2, Wr2, Wl3, Wr3, Wlin, w1, w2, w3, w4, x, xf, n4x);

    int nTiles = (N + 63) / 64;                 // 782
    int gatherBlocks = (N + 3) / 4;

    // --- layer 1: xf[128] @ w1 -> xl,xr fp16 ---
    gemm_ws<4, 2><<<dim3(128, 4), 512, 0, stream>>>(
        xf, w1, N, nTiles, 512, 256, xl, xr, nullptr, nullptr);
    gat_gather_h4<<<gatherBlocks, 256, 0, stream>>>(xl, xr, att1, b1, row_off, esrc, H, N);

    // --- layer 2: H[256] @ w2 -> xl,xr ---
    gemm_ws<8, 2><<<dim3(128, 4), 512, 0, stream>>>(
        H, w2, N, nTiles, 512, 256, xl, xr, nullptr, nullptr);
    gat_gather_h4<<<gatherBlocks, 256, 0, stream>>>(xl, xr, att2, b2, row_off, esrc, H, N);

    // --- layer 3: H[256] @ w3 -> xl,xr ([N][64] each) ---
    gemm_ws<8, 2><<<dim3(256, 1), 512, 0, stream>>>(
        H, w3, N, nTiles, 128, 64, xl, xr, nullptr, nullptr);
    gat_gather_h1<<<gatherBlocks, 256, 0, stream>>>(xl, xr, att3, b3, row_off, esrc, G, N);

    // --- final: G[64] @ w4 + blin -> d_out fp32 ---
    gemm_ws<2, 1><<<dim3(512, 1), 256, 0, stream>>>(
        G, w4, N, nTiles, 64, 64, nullptr, nullptr, (float*)d_out, blin);
}

// Round 11
// 494.724 us; speedup vs baseline: 1.2888x; 1.1222x over previous
//
#include <hip/hip_runtime.h>
#include <hip/hip_fp16.h>

#define NN 50000
#define EE 800000

typedef float f32x4 __attribute__((ext_vector_type(4)));
typedef _Float16 f16x8 __attribute__((ext_vector_type(8)));
typedef _Float16 f16x4 __attribute__((ext_vector_type(4)));
typedef _Float16 f16x2 __attribute__((ext_vector_type(2)));

// ---------------------------------------------------------------------------
// CSR build
// ---------------------------------------------------------------------------
__global__ void hist_kernel(const int* __restrict__ dst, int* __restrict__ counts, int E) {
    int idx = blockIdx.x * blockDim.x + threadIdx.x;
    int stride = gridDim.x * blockDim.x;
    for (int e = idx; e < E; e += stride)
        atomicAdd(&counts[dst[e]], 1);
}

// 3-phase parallel exclusive scan of counts[n] -> row_off[n+1]
// (R11: replaces 77us single-block serial scan)
__global__ void scan_phaseA(const int* __restrict__ counts, int* __restrict__ bsum, int n) {
    __shared__ int buf[256];
    int b = blockIdx.x, t = threadIdx.x;
    int i = b * 256 + t;
    buf[t] = (i < n) ? counts[i] : 0;
    __syncthreads();
#pragma unroll
    for (int off = 128; off; off >>= 1) {
        if (t < off) buf[t] += buf[t + off];
        __syncthreads();
    }
    if (t == 0) bsum[b] = buf[0];
}

__global__ void scan_phaseB(int* __restrict__ bsum, int* __restrict__ row_off_n, int nb) {
    __shared__ int buf[256];
    int t = threadIdx.x;
    int v = (t < nb) ? bsum[t] : 0;
    buf[t] = v;
    __syncthreads();
#pragma unroll
    for (int off = 1; off < 256; off <<= 1) {
        int x = (t >= off) ? buf[t - off] : 0;
        __syncthreads();
        buf[t] += x;
        __syncthreads();
    }
    if (t < nb) bsum[t] = buf[t] - v;       // exclusive block offset
    if (t == 255) *row_off_n = buf[255];    // total -> row_off[N]
}

__global__ void scan_phaseC(const int* __restrict__ counts, const int* __restrict__ bsum,
                            int* __restrict__ row_off, int n) {
    __shared__ int buf[256];
    int b = blockIdx.x, t = threadIdx.x;
    int i = b * 256 + t;
    int v = (i < n) ? counts[i] : 0;
    buf[t] = v;
    __syncthreads();
#pragma unroll
    for (int off = 1; off < 256; off <<= 1) {
        int x = (t >= off) ? buf[t - off] : 0;
        __syncthreads();
        buf[t] += x;
        __syncthreads();
    }
    if (i < n) row_off[i] = bsum[b] + buf[t] - v;
}

__global__ void scatter_kernel(const int* __restrict__ src, const int* __restrict__ dst,
                               const int* __restrict__ row_off, int* __restrict__ cursor,
                               int* __restrict__ esrc, int E) {
    int idx = blockIdx.x * blockDim.x + threadIdx.x;
    int stride = gridDim.x * blockDim.x;
    for (int e = idx; e < E; e += stride) {
        int d = dst[e];
        int pos = row_off[d] + atomicAdd(&cursor[d], 1);
        esrc[pos] = src[e];
    }
}

// ---------------------------------------------------------------------------
// Fused prep: weights -> FRAGMENT-READY fp16 layout, x -> fp16.
//   col -> cgni = col>>4, l15 = col&15 ; k -> ks = k>>5, q=(k>>3)&3, e=k&7
//   flat = ((cgni*KS + ks)*64 + q*16 + l15)*8 + e
// so a wave's bfrag[ks][ni] load is 64 lanes x consecutive 16B = 1KB burst.
// ---------------------------------------------------------------------------
__device__ __forceinline__ void wfrag_store(__half* o, int K, int col, int k, float v) {
    int KS = K >> 5;
    int cgni = col >> 4, l15 = col & 15;
    int ks = k >> 5, qq = (k >> 3) & 3, ee = k & 7;
    size_t flat = ((size_t)(cgni * KS + ks) * 64 + qq * 16 + l15) * 8 + ee;
    o[flat] = __float2half_rn(v);
}

__global__ void prep_all(const float* __restrict__ Wl1, const float* __restrict__ Wr1,
                         const float* __restrict__ Wl2, const float* __restrict__ Wr2,
                         const float* __restrict__ Wl3, const float* __restrict__ Wr3,
                         const float* __restrict__ Wlin,
                         __half* __restrict__ w1, __half* __restrict__ w2,
                         __half* __restrict__ w3, __half* __restrict__ w4,
                         const float* __restrict__ x, __half* __restrict__ xf, int n4x) {
    int idx = blockIdx.x * blockDim.x + threadIdx.x;
    if (idx < 233472) {
        const float* W; __half* o; int K, Nc, roff, li;
        if (idx < 65536) {
            K = 128; Nc = 256; o = w1;
            if (idx < 32768) { W = Wl1; li = idx; roff = 0; }
            else             { W = Wr1; li = idx - 32768; roff = 256; }
        } else if (idx < 196608) {
            K = 256; Nc = 256; o = w2;
            if (idx < 131072) { W = Wl2; li = idx - 65536; roff = 0; }
            else              { W = Wr2; li = idx - 131072; roff = 256; }
        } else if (idx < 229376) {
            K = 256; Nc = 64; o = w3;
            if (idx < 212992) { W = Wl3; li = idx - 196608; roff = 0; }
            else              { W = Wr3; li = idx - 212992; roff = 64; }
        } else {
            K = 64; Nc = 64; o = w4; W = Wlin; li = idx - 229376; roff = 0;
        }
        int k = li / Nc, n = li - k * Nc;
        wfrag_store(o, K, roff + n, k, W[li]);
    } else {
        int xi = idx - 233472;
        if (xi < n4x) {
            float4 v = *(const float4*)(x + (size_t)xi * 4);
            f16x4 h = {(_Float16)v.x, (_Float16)v.y, (_Float16)v.z, (_Float16)v.w};
            *(f16x4*)((_Float16*)xf + (size_t)xi * 4) = h;
        }
    }
}

// ---------------------------------------------------------------------------
// Weight-stationary tall-skinny GEMM: no LDS, no barriers. B pre-permuted
// to fragment-ready layout (coalesced 1KB bursts). A global->reg in MFMA
// layout. Grid-stride tiles with A double-buffer.
// ---------------------------------------------------------------------------
template <int KS, int COLG>
__global__ __launch_bounds__(COLG * 256) void gemm_ws(
        const __half* __restrict__ A, const __half* __restrict__ Bt,
        int M, int nTiles, int Nc, int splitCol,
        __half* __restrict__ outL, __half* __restrict__ outR,
        float* __restrict__ outF, const float* __restrict__ bias) {
    constexpr int K = KS * 32;
    int tid = threadIdx.x;
    int lane = tid & 63;
    int w = tid >> 6;
    int rs = w & 3;
    int cg = w >> 2;
    int l15 = lane & 15, q = lane >> 4;
    int colbase = blockIdx.y * (COLG * 64) + cg * 64;

    const _Float16* Ap = (const _Float16*)A;
    const f16x8* Bf = (const f16x8*)Bt;
    int cgni0 = (blockIdx.y * COLG + cg) * 4;

    f16x8 bfrag[KS][4];
#pragma unroll
    for (int ks = 0; ks < KS; ++ks)
#pragma unroll
        for (int ni = 0; ni < 4; ++ni)
            bfrag[ks][ni] = Bf[((size_t)(cgni0 + ni) * KS + ks) * 64 + lane];

    int tile = blockIdx.x;
    if (tile >= nTiles) return;

    f16x8 afrag[KS];
    {
        int row = tile * 64 + rs * 16 + l15;
        if (row >= M) row = M - 1;
        const _Float16* ap = Ap + (size_t)row * K + q * 8;
#pragma unroll
        for (int ks = 0; ks < KS; ++ks) afrag[ks] = *(const f16x8*)(ap + ks * 32);
    }

    while (true) {
        int next = tile + gridDim.x;
        bool has = (next < nTiles);
        f16x8 anext[KS];
        if (has) {
            int row = next * 64 + rs * 16 + l15;
            if (row >= M) row = M - 1;
            const _Float16* ap = Ap + (size_t)row * K + q * 8;
#pragma unroll
            for (int ks = 0; ks < KS; ++ks) anext[ks] = *(const f16x8*)(ap + ks * 32);
        }

        f32x4 acc[4] = {};
#pragma unroll
        for (int ks = 0; ks < KS; ++ks)
#pragma unroll
            for (int ni = 0; ni < 4; ++ni)
                acc[ni] = __builtin_amdgcn_mfma_f32_16x16x32_f16(afrag[ks], bfrag[ks][ni], acc[ni], 0, 0, 0);

#pragma unroll
        for (int ni = 0; ni < 4; ++ni) {
            int gc = colbase + ni * 16 + l15;
            if (outF) {
                float bv = bias ? bias[gc] : 0.f;
#pragma unroll
                for (int r = 0; r < 4; ++r) {
                    int gr = tile * 64 + rs * 16 + q * 4 + r;
                    if (gr < M) outF[(size_t)gr * Nc + gc] = acc[ni][r] + bv;
                }
            } else {
                __half* dp = outL; int cc = gc;
                if (gc >= splitCol) { dp = outR; cc = gc - splitCol; }
#pragma unroll
                for (int r = 0; r < 4; ++r) {
                    int gr = tile * 64 + rs * 16 + q * 4 + r;
                    if (gr < M) dp[(size_t)gr * splitCol + cc] = __float2half_rn(acc[ni][r]);
                }
            }
        }
        if (!has) break;
#pragma unroll
        for (int ks = 0; ks < KS; ++ks) afrag[ks] = anext[ks];
        tile = next;
    }
}

// ---------------------------------------------------------------------------
// GATv2 gather, H=4 x C=64, fp16 in/out. One wave per dst node, 2 edges per
// wave-pass (half-waves), unroll x2; 32-bit offsets, fma_mix accumulation,
// exp2f with pre-scaled att.
// ---------------------------------------------------------------------------
__global__ __launch_bounds__(256) void gat_gather_h4(
        const __half* __restrict__ xl, const __half* __restrict__ xr,
        const float* __restrict__ att, const float* __restrict__ bias,
        const int* __restrict__ row_off, const int* __restrict__ esrc,
        __half* __restrict__ out, int n) {
    const float LOG2E = 1.44269504f;
    int wave = threadIdx.x >> 6;
    int lane = threadIdx.x & 63;
    int node = blockIdx.x * 4 + wave;
    if (node >= n) return;
    int half = lane >> 5;
    unsigned j = lane & 31;

    const uint4* xl4 = (const uint4*)xl;
    uint4 xraw = ((const uint4*)xr)[((unsigned)node << 5) + j];
    f16x2 xrv[4] = {*(const f16x2*)&xraw.x, *(const f16x2*)&xraw.y,
                    *(const f16x2*)&xraw.z, *(const f16x2*)&xraw.w};
    float4 aA = *(const float4*)(att + j * 8);
    float4 aB = *(const float4*)(att + j * 8 + 4);
    f16x2 atv[4] = {{(_Float16)(aA.x * LOG2E), (_Float16)(aA.y * LOG2E)},
                    {(_Float16)(aA.z * LOG2E), (_Float16)(aA.w * LOG2E)},
                    {(_Float16)(aB.x * LOG2E), (_Float16)(aB.y * LOG2E)},
                    {(_Float16)(aB.z * LOG2E), (_Float16)(aB.w * LOG2E)}};
    const f16x2 k02 = {(_Float16)0.2f, (_Float16)0.2f};

    float acc0[8] = {}, acc1[8] = {};
    float l0 = 0.f, l1 = 0.f;

    int e0 = row_off[node], e1 = row_off[node + 1];
    int elast = e1 - 1;

#define H4_BODY(EBASE, ACC, LSUM)                                             \
    {                                                                         \
        int idx_ = EBASE + half;                                              \
        int s_ = esrc[min(idx_, elast)];                                      \
        uint4 raw_ = xl4[((unsigned)s_ << 5) + j];                            \
        f16x2 v0_ = *(const f16x2*)&raw_.x;                                   \
        f16x2 v1_ = *(const f16x2*)&raw_.y;                                   \
        f16x2 v2_ = *(const f16x2*)&raw_.z;                                   \
        f16x2 v3_ = *(const f16x2*)&raw_.w;                                   \
        f16x2 s0_ = v0_ + xrv[0], s1_ = v1_ + xrv[1];                         \
        f16x2 s2_ = v2_ + xrv[2], s3_ = v3_ + xrv[3];                         \
        f16x2 r0_ = __builtin_elementwise_max(s0_, s0_ * k02);                \
        f16x2 r1_ = __builtin_elementwise_max(s1_, s1_ * k02);                \
        f16x2 r2_ = __builtin_elementwise_max(s2_, s2_ * k02);                \
        f16x2 r3_ = __builtin_elementwise_max(s3_, s3_ * k02);                \
        float t_ = __builtin_amdgcn_fdot2(r0_, atv[0], 0.f, false);           \
        t_ = __builtin_amdgcn_fdot2(r1_, atv[1], t_, false);                  \
        t_ = __builtin_amdgcn_fdot2(r2_, atv[2], t_, false);                  \
        t_ = __builtin_amdgcn_fdot2(r3_, atv[3], t_, false);                  \
        t_ += __shfl_xor(t_, 1);                                              \
        t_ += __shfl_xor(t_, 2);                                              \
        t_ += __shfl_xor(t_, 4);                                              \
        float p_ = exp2f(t_);                                                 \
        p_ = (idx_ < e1) ? p_ : 0.f;                                          \
        LSUM += p_;                                                           \
        ACC[0] = fmaf((float)v0_.x, p_, ACC[0]);                              \
        ACC[1] = fmaf((float)v0_.y, p_, ACC[1]);                              \
        ACC[2] = fmaf((float)v1_.x, p_, ACC[2]);                              \
        ACC[3] = fmaf((float)v1_.y, p_, ACC[3]);                              \
        ACC[4] = fmaf((float)v2_.x, p_, ACC[4]);                              \
        ACC[5] = fmaf((float)v2_.y, p_, ACC[5]);                              \
        ACC[6] = fmaf((float)v3_.x, p_, ACC[6]);                              \
        ACC[7] = fmaf((float)v3_.y, p_, ACC[7]);                              \
    }

    for (int e = e0; e < e1; e += 4) {
        H4_BODY(e, acc0, l0)
        if (e + 2 < e1) H4_BODY(e + 2, acc1, l1)
    }
#undef H4_BODY

    float acc[8];
#pragma unroll
    for (int k = 0; k < 8; ++k) acc[k] = acc0[k] + acc1[k];
    float L = l0 + l1;
#pragma unroll
    for (int k = 0; k < 8; ++k) acc[k] += __shfl_xor(acc[k], 32);
    L += __shfl_xor(L, 32);

    float inv = 1.f / (L + 1e-16f);
    float4 bvA = *(const float4*)(bias + j * 8);
    float4 bvB = *(const float4*)(bias + j * 8 + 4);
    float bb[8] = {bvA.x, bvA.y, bvA.z, bvA.w, bvB.x, bvB.y, bvB.z, bvB.w};
    f16x8 ov;
#pragma unroll
    for (int k = 0; k < 8; ++k) {
        float v = acc[k] * inv + bb[k];
        v = v > 0.f ? v : __expf(v) - 1.f;   // ELU
        ov[k] = (_Float16)v;
    }
    if (half == 0)
        ((f16x8*)((_Float16*)out + ((size_t)node << 8)))[j] = ov;
}

// ---------------------------------------------------------------------------
// GATv2 gather, H=1 x C=64, fp16 in/out (no ELU). 4 edges per pass.
// ---------------------------------------------------------------------------
__global__ __launch_bounds__(256) void gat_gather_h1(
        const __half* __restrict__ xl, const __half* __restrict__ xr,
        const float* __restrict__ att, const float* __restrict__ bias,
        const int* __restrict__ row_off, const int* __restrict__ esrc,
        __half* __restrict__ out, int n) {
    const float LOG2E = 1.44269504f;
    int wave = threadIdx.x >> 6;
    int lane = threadIdx.x & 63;
    int node = blockIdx.x * 4 + wave;
    if (node >= n) return;
    int q4 = lane >> 4;
    unsigned j = lane & 15;

    const uint2* xl2 = (const uint2*)xl;
    uint2 xraw = ((const uint2*)xr)[((unsigned)node << 4) + j];
    f16x2 xrv[2] = {*(const f16x2*)&xraw.x, *(const f16x2*)&xraw.y};
    float4 av = *(const float4*)(att + j * 4);
    f16x2 atv[2] = {{(_Float16)(av.x * LOG2E), (_Float16)(av.y * LOG2E)},
                    {(_Float16)(av.z * LOG2E), (_Float16)(av.w * LOG2E)}};
    const f16x2 k02 = {(_Float16)0.2f, (_Float16)0.2f};

    float acc0[4] = {}, acc1[4] = {};
    float l0 = 0.f, l1 = 0.f;

    int e0 = row_off[node], e1 = row_off[node + 1];
    int elast = e1 - 1;

#define H1_BODY(EBASE, ACC, LSUM)                                             \
    {                                                                         \
        int idx_ = EBASE + q4;                                                \
        int s_ = esrc[min(idx_, elast)];                                      \
        uint2 raw_ = xl2[((unsigned)s_ << 4) + j];                            \
        f16x2 v0_ = *(const f16x2*)&raw_.x;                                   \
        f16x2 v1_ = *(const f16x2*)&raw_.y;                                   \
        f16x2 s0_ = v0_ + xrv[0], s1_ = v1_ + xrv[1];                         \
        f16x2 r0_ = __builtin_elementwise_max(s0_, s0_ * k02);                \
        f16x2 r1_ = __builtin_elementwise_max(s1_, s1_ * k02);                \
        float t_ = __builtin_amdgcn_fdot2(r0_, atv[0], 0.f, false);           \
        t_ = __builtin_amdgcn_fdot2(r1_, atv[1], t_, false);                  \
        t_ += __shfl_xor(t_, 1);                                              \
        t_ += __shfl_xor(t_, 2);                                              \
        t_ += __shfl_xor(t_, 4);                                              \
        t_ += __shfl_xor(t_, 8);                                              \
        float p_ = exp2f(t_);                                                 \
        p_ = (idx_ < e1) ? p_ : 0.f;                                          \
        LSUM += p_;                                                           \
        ACC[0] = fmaf((float)v0_.x, p_, ACC[0]);                              \
        ACC[1] = fmaf((float)v0_.y, p_, ACC[1]);                              \
        ACC[2] = fmaf((float)v1_.x, p_, ACC[2]);                              \
        ACC[3] = fmaf((float)v1_.y, p_, ACC[3]);                              \
    }

    for (int e = e0; e < e1; e += 8) {
        H1_BODY(e, acc0, l0)
        if (e + 4 < e1) H1_BODY(e + 4, acc1, l1)
    }
#undef H1_BODY

    float acc[4];
#pragma unroll
    for (int k = 0; k < 4; ++k) acc[k] = acc0[k] + acc1[k];
    float L = l0 + l1;
#pragma unroll
    for (int k = 0; k < 4; ++k) {
        acc[k] += __shfl_xor(acc[k], 16);
        acc[k] += __shfl_xor(acc[k], 32);
    }
    L += __shfl_xor(L, 16);
    L += __shfl_xor(L, 32);

    float inv = 1.f / (L + 1e-16f);
    float4 bv = *(const float4*)(bias + j * 4);
    f16x4 ov = {(_Float16)(acc[0] * inv + bv.x),
                (_Float16)(acc[1] * inv + bv.y),
                (_Float16)(acc[2] * inv + bv.z),
                (_Float16)(acc[3] * inv + bv.w)};
    if (q4 == 0)
        ((f16x4*)((_Float16*)out + ((size_t)node << 6)))[j] = ov;
}

// ---------------------------------------------------------------------------
extern "C" void kernel_launch(void* const* d_in, const int* in_sizes, int n_in,
                              void* d_out, int out_size, void* d_ws, size_t ws_size,
                              hipStream_t stream) {
    const float* x    = (const float*)d_in[0];
    const float* Wl1  = (const float*)d_in[1];
    const float* Wr1  = (const float*)d_in[2];
    const float* att1 = (const float*)d_in[3];
    const float* b1   = (const float*)d_in[4];
    const float* Wl2  = (const float*)d_in[5];
    const float* Wr2  = (const float*)d_in[6];
    const float* att2 = (const float*)d_in[7];
    const float* b2   = (const float*)d_in[8];
    const float* Wl3  = (const float*)d_in[9];
    const float* Wr3  = (const float*)d_in[10];
    const float* att3 = (const float*)d_in[11];
    const float* b3   = (const float*)d_in[12];
    const float* Wlin = (const float*)d_in[13];
    const float* blin = (const float*)d_in[14];
    const int*   ei   = (const int*)d_in[15];
    const int* src = ei;
    const int* dst = ei + EE;

    const int N = NN, E = EE;
    const int NB = (N + 255) / 256;             // 196 scan blocks

    __half* xf = (__half*)d_ws;                 // N*128
    __half* xl = xf + (size_t)N * 128;          // N*256
    __half* xr = xl + (size_t)N * 256;          // N*256
    __half* H  = xr + (size_t)N * 256;          // N*256
    __half* G  = H + (size_t)N * 256;           // N*64
    __half* w1 = G + (size_t)N * 64;            // 65536  frag-layout
    __half* w2 = w1 + 65536;                    // 131072
    __half* w3 = w2 + 131072;                   // 32768
    __half* w4 = w3 + 32768;                    // 4096
    int* row_off = (int*)(w4 + 4096);           // N+1
    int* tmp     = row_off + (N + 1);           // 2N (counts | cursor)
    int* esrc    = tmp + 2 * N;                 // E
    int* bsum    = esrc + E;                    // 256

    // --- build CSR by dst ---
    hipMemsetAsync(tmp, 0, (size_t)2 * N * sizeof(int), stream);
    hist_kernel<<<1024, 256, 0, stream>>>(dst, tmp, E);
    scan_phaseA<<<NB, 256, 0, stream>>>(tmp, bsum, N);
    scan_phaseB<<<1, 256, 0, stream>>>(bsum, row_off + N, NB);
    scan_phaseC<<<NB, 256, 0, stream>>>(tmp, bsum, row_off, N);
    scatter_kernel<<<1024, 256, 0, stream>>>(src, dst, row_off, tmp + N, esrc, E);

    // --- weights (fragment layout) + x -> fp16 ---
    int n4x = N * 128 / 4;
    prep_all<<<(233472 + n4x + 255) / 256, 256, 0, stream>>>(
        Wl1, Wr1, Wl2, Wr2, Wl3, Wr3, Wlin, w1, w2, w3, w4, x, xf, n4x);

    int nTiles = (N + 63) / 64;                 // 782
    int gatherBlocks = (N + 3) / 4;

    // --- layer 1: xf[128] @ w1 -> xl,xr fp16 ---
    gemm_ws<4, 2><<<dim3(128, 4), 512, 0, stream>>>(
        xf, w1, N, nTiles, 512, 256, xl, xr, nullptr, nullptr);
    gat_gather_h4<<<gatherBlocks, 256, 0, stream>>>(xl, xr, att1, b1, row_off, esrc, H, N);

    // --- layer 2: H[256] @ w2 -> xl,xr ---
    gemm_ws<8, 2><<<dim3(128, 4), 512, 0, stream>>>(
        H, w2, N, nTiles, 512, 256, xl, xr, nullptr, nullptr);
    gat_gather_h4<<<gatherBlocks, 256, 0, stream>>>(xl, xr, att2, b2, row_off, esrc, H, N);

    // --- layer 3: H[256] @ w3 -> xl,xr ([N][64] each) ---
    gemm_ws<8, 2><<<dim3(256, 1), 512, 0, stream>>>(
        H, w3, N, nTiles, 128, 64, xl, xr, nullptr, nullptr);
    gat_gather_h1<<<gatherBlocks, 256, 0, stream>>>(xl, xr, att3, b3, row_off, esrc, G, N);

    // --- final: G[64] @ w4 + blin -> d_out fp32 ---
    gemm_ws<2, 1><<<dim3(512, 1), 256, 0, stream>>>(
        G, w4, N, nTiles, 64, 64, nullptr, nullptr, (float*)d_out, blin);
}